// Round 4
// baseline (618.171 us; speedup 1.0000x reference)
//
#include <hip/hip_runtime.h>
#include <hip/hip_bf16.h>
#include <stdint.h>

typedef unsigned short u16;
typedef __bf16 bf16_t;
typedef bf16_t bf16x8 __attribute__((ext_vector_type(8)));
typedef u16    u16x8  __attribute__((ext_vector_type(8)));
typedef u16    u16x4  __attribute__((ext_vector_type(4)));
typedef float  f32x4  __attribute__((ext_vector_type(4)));

#define BSZ    256
#define NATOMS 128
#define INF    128
#define HH     256
#define H3     768
#define MAXV   6
#define OUTF   256
#define KFC    (HH * MAXV)      // 1536
#define PLANE  8388608          // u16 elems per xp2 gate plane: 16*128*8*64*8

__device__ __forceinline__ u16 f2bf(float f) {
  union { float f; unsigned u; } v; v.f = f;
  unsigned u = v.u;
  unsigned r = (u + 0x7FFFu + ((u >> 16) & 1u)) >> 16;  // RNE
  return (u16)r;
}
__device__ __forceinline__ float bf2f(u16 h) {
  union { unsigned u; float f; } v; v.u = ((unsigned)h) << 16;
  return v.f;
}
__device__ __forceinline__ f32x4 mfma_bf16(u16x8 a, u16x8 b, f32x4 c) {
  return __builtin_amdgcn_mfma_f32_16x16x32_bf16(
      __builtin_bit_cast(bf16x8, a), __builtin_bit_cast(bf16x8, b), c, 0, 0, 0);
}
// async global->LDS, 16B/lane; HW dest = wave-uniform base + lane*16
#define GLDS(gp, lp)                                                        \
  __builtin_amdgcn_global_load_lds(                                         \
      (const __attribute__((address_space(1))) uint32_t*)(uintptr_t)(gp),   \
      (__attribute__((address_space(3))) uint32_t*)(uintptr_t)(lp), 16, 0, 0)

// ---------------- prep: W_hh and W_fc fp32 -> bf16 ----------------
__global__ void k_prep(const float* __restrict__ whh, u16* __restrict__ whho,
                       const float* __restrict__ wfc, u16* __restrict__ wfco) {
  int i = blockIdx.x * 256 + threadIdx.x;
  if (i < H3 * HH) whho[i] = f2bf(whh[i]);
  if (i < OUTF * KFC) wfco[i] = f2bf(wfc[i]);
}

// ---------------- stage 1: xp2 = x @ W_ih^T + bih (+bhh for r,z gates) ------
// Output layout (3 gate planes, matched to k_gru's lane/wave mapping):
//   plane g, u16 index: ((bb*128 + t)*8 + w)*512 + L*8 + p*4 + r
//   where b=bb*16+mb, L=(mb>>2)*16+c, r=mb&3, n = g*256 + w*32 + p*16 + c.
__global__ __launch_bounds__(256) void k_xproj(const float* __restrict__ X,
                                               const float* __restrict__ W,
                                               const float* __restrict__ bias,
                                               const float* __restrict__ bhh,
                                               u16* __restrict__ out) {
  __shared__ __align__(16) u16 As[64][40];
  __shared__ __align__(16) u16 Bs[64][40];
  const int m0 = blockIdx.x * 64, n0 = blockIdx.y * 64;
  const int tid = threadIdx.x, lane = tid & 63, wid = tid >> 6;
  const int wm = (wid & 1) * 32, wn = (wid >> 1) * 32;
  const int lrow = tid >> 2, lcol = (tid & 3) * 8;
  const f32x4 zero = {0.f, 0.f, 0.f, 0.f};
  f32x4 acc[2][2];
#pragma unroll
  for (int mi = 0; mi < 2; mi++)
#pragma unroll
    for (int ni = 0; ni < 2; ni++) acc[mi][ni] = zero;

  for (int kk = 0; kk < INF; kk += 32) {
    const float* ap = X + (size_t)(m0 + lrow) * INF + kk + lcol;
    const float* bp = W + (size_t)(n0 + lrow) * INF + kk + lcol;
    u16x8 av, bv;
#pragma unroll
    for (int j = 0; j < 8; j++) { av[j] = f2bf(ap[j]); bv[j] = f2bf(bp[j]); }
    *(u16x8*)&As[lrow][lcol] = av;
    *(u16x8*)&Bs[lrow][lcol] = bv;
    __syncthreads();
    u16x8 afr[2], bfr[2];
#pragma unroll
    for (int mi = 0; mi < 2; mi++)
      afr[mi] = *(const u16x8*)&As[wm + mi * 16 + (lane & 15)][(lane >> 4) * 8];
#pragma unroll
    for (int ni = 0; ni < 2; ni++)
      bfr[ni] = *(const u16x8*)&Bs[wn + ni * 16 + (lane & 15)][(lane >> 4) * 8];
#pragma unroll
    for (int mi = 0; mi < 2; mi++)
#pragma unroll
      for (int ni = 0; ni < 2; ni++) acc[mi][ni] = mfma_bf16(afr[mi], bfr[ni], acc[mi][ni]);
    __syncthreads();
  }
#pragma unroll
  for (int mi = 0; mi < 2; mi++)
#pragma unroll
    for (int ni = 0; ni < 2; ni++) {
      const int n = n0 + wn + ni * 16 + (lane & 15);
      const int g = n >> 8, i2 = n & 255;
      const int ww = i2 >> 5, ii = i2 & 31, pp = ii >> 4, cc = ii & 15;
      const float badd = bias[n] + (g < 2 ? bhh[n] : 0.f);  // fold bhh into r,z
      u16* plane = out + (size_t)g * PLANE;
#pragma unroll
      for (int r = 0; r < 4; r++) {
        const int m = m0 + wm + mi * 16 + (lane >> 4) * 4 + r;  // m = b*128 + t
        const int b = m >> 7, t = m & 127, bb = b >> 4, mb = b & 15;
        const size_t off = ((size_t)((bb * 128 + t) * 8 + ww) << 9) +
                           ((((mb >> 2) << 4) | cc) << 3) + pp * 4 + (mb & 3);
        plane[off] = f2bf(acc[mi][ni][r] + badd);
      }
    }
}

// ---------------- stage 2: GRU recurrence -----------------------------------
// 16 blocks x 512 thr (8 waves, 2/EU); block owns 16 batches (M=16 full).
// Wave w owns W_hh rows {g*256 + w*32 .. +32} for g=r,z,n -> each lane's MFMA
// D-fragments hold the matching (hr,hz,hn) triple => gates fully in-register.
// hA and xp-LDS double-buffered => 1 barrier/step; xp prefetched 1 step ahead
// via global_load_lds (no dependence on h).
__global__ void __attribute__((amdgpu_flat_work_group_size(512, 512),
                               amdgpu_waves_per_eu(2, 2)))
k_gru(const u16* __restrict__ Whh, const float* __restrict__ bhh,
      const u16* __restrict__ xp2, u16* __restrict__ rnn) {
  __shared__ __align__(16) u16 hA[2][16 * 264];       // bf16 h, A-layout, dbuf
  __shared__ __align__(16) u16 xpb[2][3][8][64][8];   // xp stage, dbuf, 48 KB
  const int tid = threadIdx.x, lane = tid & 63, w = tid >> 6;  // w in [0,8)
  const int c = lane & 15, quad = lane >> 4;
  const int b0 = blockIdx.x * 16;

  for (int i = tid; i < 2 * 16 * 264; i += 512) ((u16*)hA)[i] = 0;

  // W_hh fragments: 6 tiles (g2 = gate*2 + p) x 8 k-frags = 192 regs
  u16x8 wf[6][8];
#pragma unroll
  for (int g2 = 0; g2 < 6; g2++)
#pragma unroll
    for (int kt = 0; kt < 8; kt++) {
      const int n = (g2 >> 1) * 256 + w * 32 + (g2 & 1) * 16 + c;
      wf[g2][kt] = *(const u16x8*)(Whh + (size_t)n * HH + kt * 32 + quad * 8);
    }
#pragma unroll
  for (int g2 = 0; g2 < 6; g2++)
#pragma unroll
    for (int kt = 0; kt < 8; kt++) asm volatile("" : "+v"(wf[g2][kt]));

  const float bhhn[2] = { bhh[512 + w * 32 + c], bhh[512 + w * 32 + 16 + c] };
  float hreg[8] = {0.f, 0.f, 0.f, 0.f, 0.f, 0.f, 0.f, 0.f};

  // global xp base for this (block=bb, wave, lane); +4096 u16 per t
  const u16* gbase = xp2 + ((size_t)(blockIdx.x * 128) * 8 + w) * 512 + lane * 8;
  const unsigned rnnA = (unsigned)((b0 + quad * 4) * (NATOMS * HH) + w * 32 + c);

  // prefetch t=0
#pragma unroll
  for (int g = 0; g < 3; g++)
    GLDS(gbase + (size_t)g * PLANE, &xpb[0][g][w][0][0]);

  __syncthreads();

  const f32x4 zero4 = {0.f, 0.f, 0.f, 0.f};
#pragma unroll 1
  for (int t = 0; t < NATOMS; t++) {
    const u16* hc = hA[t & 1];
    u16* hnx = hA[(t + 1) & 1];
    // prefetch xp for t+1 into the other LDS buffer (no race with reads of t)
    if (t < NATOMS - 1) {
      const u16* gp = gbase + (size_t)(t + 1) * 4096;
#pragma unroll
      for (int g = 0; g < 3; g++)
        GLDS(gp + (size_t)g * PLANE, &xpb[(t + 1) & 1][g][w][0][0]);
    }
    // A-fragments of h (all 8 resident: 32 regs)
    u16x8 af[8];
#pragma unroll
    for (int kt = 0; kt < 8; kt++)
      af[kt] = *(const u16x8*)&hc[c * 264 + kt * 32 + quad * 8];

    // ---- half p=0: tiles wf[0],wf[2],wf[4] ----
    f32x4 accA[3] = {zero4, zero4, zero4};
#pragma unroll
    for (int kt = 0; kt < 8; kt++)
#pragma unroll
      for (int g = 0; g < 3; g++)
        accA[g] = mfma_bf16(af[kt], wf[g * 2][kt], accA[g]);
    u16x4 xg0[3];
#pragma unroll
    for (int g = 0; g < 3; g++)
      xg0[g] = *(const u16x4*)&xpb[t & 1][g][w][lane][0];
#pragma unroll
    for (int r_ = 0; r_ < 4; r_++) {
      const float ar = accA[0][r_] + bf2f(xg0[0][r_]);   // bih+bhh pre-folded
      const float az = accA[1][r_] + bf2f(xg0[1][r_]);
      const float hn = accA[2][r_] + bhhn[0];
      const float xn = bf2f(xg0[2][r_]);
      const float rr = 1.f / (1.f + __expf(-ar));
      const float zz = 1.f / (1.f + __expf(-az));
      const float e  = __expf(2.f * (xn + rr * hn));
      const float nn = 1.f - 2.f / (e + 1.f);
      const float hv = nn + zz * (hreg[r_] - nn);
      hreg[r_] = hv;
      const u16 hb = f2bf(hv);
      hnx[(quad * 4 + r_) * 264 + w * 32 + c] = hb;
      rnn[rnnA + r_ * 32768u + (unsigned)t * 256u] = hb;
    }

    // ---- half p=1: tiles wf[1],wf[3],wf[5] ----
    f32x4 accB[3] = {zero4, zero4, zero4};
#pragma unroll
    for (int kt = 0; kt < 8; kt++)
#pragma unroll
      for (int g = 0; g < 3; g++)
        accB[g] = mfma_bf16(af[kt], wf[g * 2 + 1][kt], accB[g]);
    u16x4 xg1[3];
#pragma unroll
    for (int g = 0; g < 3; g++)
      xg1[g] = *(const u16x4*)&xpb[t & 1][g][w][lane][4];
#pragma unroll
    for (int r_ = 0; r_ < 4; r_++) {
      const float ar = accB[0][r_] + bf2f(xg1[0][r_]);
      const float az = accB[1][r_] + bf2f(xg1[1][r_]);
      const float hn = accB[2][r_] + bhhn[1];
      const float xn = bf2f(xg1[2][r_]);
      const float rr = 1.f / (1.f + __expf(-ar));
      const float zz = 1.f / (1.f + __expf(-az));
      const float e  = __expf(2.f * (xn + rr * hn));
      const float nn = 1.f - 2.f / (e + 1.f);
      const float hv = nn + zz * (hreg[4 + r_] - nn);
      hreg[4 + r_] = hv;
      const u16 hb = f2bf(hv);
      hnx[(quad * 4 + r_) * 264 + w * 32 + 16 + c] = hb;
      rnn[rnnA + r_ * 32768u + (unsigned)t * 256u + 16u] = hb;
    }
    __syncthreads();
  }
}

// ---------------- stage 3: out = leaky(gather(rnn) @ W_fc^T + b_fc) ---------
__global__ __launch_bounds__(256) void k_fc(const u16* __restrict__ rnn,
                                            const int* __restrict__ bonded,
                                            const u16* __restrict__ W,
                                            const float* __restrict__ bias,
                                            float* __restrict__ out) {
  __shared__ __align__(16) u16 As[64][40];
  __shared__ __align__(16) u16 Bs[64][40];
  const int m0 = blockIdx.x * 64, n0 = blockIdx.y * 64;
  const int tid = threadIdx.x, lane = tid & 63, wid = tid >> 6;
  const int wm = (wid & 1) * 32, wn = (wid >> 1) * 32;
  const int lrow = tid >> 2, lcol = (tid & 3) * 8;
  const int m = m0 + lrow;
  const int b = m >> 7, atom = m & 127;
  const int* bptr = bonded + (size_t)(b * NATOMS + atom) * MAXV;
  const f32x4 zero = {0.f, 0.f, 0.f, 0.f};
  f32x4 acc[2][2];
#pragma unroll
  for (int mi = 0; mi < 2; mi++)
#pragma unroll
    for (int ni = 0; ni < 2; ni++) acc[mi][ni] = zero;

  for (int kk = 0; kk < KFC; kk += 32) {
    int k = kk + lcol;
    int v = k >> 8, kr = k & 255;
    int idx = bptr[v];
    u16x8 av = *(const u16x8*)(rnn + (size_t)(b * NATOMS + idx) * HH + kr);
    u16x8 bv = *(const u16x8*)(W + (size_t)(n0 + lrow) * KFC + k);
    *(u16x8*)&As[lrow][lcol] = av;
    *(u16x8*)&Bs[lrow][lcol] = bv;
    __syncthreads();
    u16x8 afr[2], bfr[2];
#pragma unroll
    for (int mi = 0; mi < 2; mi++)
      afr[mi] = *(const u16x8*)&As[wm + mi * 16 + (lane & 15)][(lane >> 4) * 8];
#pragma unroll
    for (int ni = 0; ni < 2; ni++)
      bfr[ni] = *(const u16x8*)&Bs[wn + ni * 16 + (lane & 15)][(lane >> 4) * 8];
#pragma unroll
    for (int mi = 0; mi < 2; mi++)
#pragma unroll
      for (int ni = 0; ni < 2; ni++) acc[mi][ni] = mfma_bf16(afr[mi], bfr[ni], acc[mi][ni]);
    __syncthreads();
  }
#pragma unroll
  for (int mi = 0; mi < 2; mi++)
#pragma unroll
    for (int ni = 0; ni < 2; ni++) {
      int n = n0 + wn + ni * 16 + (lane & 15);
      float bv = bias[n];
#pragma unroll
      for (int r = 0; r < 4; r++) {
        int mm = m0 + wm + mi * 16 + (lane >> 4) * 4 + r;
        float vv = acc[mi][ni][r] + bv;
        out[(size_t)mm * OUTF + n] = vv >= 0.f ? vv : 0.1f * vv;
      }
    }
}

extern "C" void kernel_launch(void* const* d_in, const int* in_sizes, int n_in,
                              void* d_out, int out_size, void* d_ws, size_t ws_size,
                              hipStream_t stream) {
  const float* x      = (const float*)d_in[0];
  const int*   bonded = (const int*)d_in[1];
  const float* Wih    = (const float*)d_in[2];
  const float* Whh    = (const float*)d_in[3];
  const float* bih    = (const float*)d_in[4];
  const float* bhh    = (const float*)d_in[5];
  const float* Wfc    = (const float*)d_in[6];
  const float* bfc    = (const float*)d_in[7];
  float* out = (float*)d_out;

  char* ws = (char*)d_ws;
  u16* xp2  = (u16*)(ws);                                    // 3*16MB = 50,331,648 B
  u16* rnn  = (u16*)(ws + 50331648);                         // 16,777,216 B
  u16* whhb = (u16*)(ws + 50331648 + 16777216);              //    393,216 B
  u16* wfcb = (u16*)(ws + 50331648 + 16777216 + 393216);     //    786,432 B

  k_prep<<<(OUTF * KFC + 255) / 256, 256, 0, stream>>>(Whh, whhb, Wfc, wfcb);
  k_xproj<<<dim3(512, 12), 256, 0, stream>>>(x, Wih, bih, bhh, xp2);
  k_gru<<<16, 512, 0, stream>>>(whhb, bhh, xp2, rnn);
  k_fc<<<dim3(512, 4), 256, 0, stream>>>(rnn, bonded, wfcb, bfc, out);
}